// Round 1
// baseline (474.130 us; speedup 1.0000x reference)
//
#include <hip/hip_runtime.h>
#include <cstdint>

#define NN 4096
#define FIN 512
#define DD 64
#define HH 8
#define CC 16
#define KHOP 2
#define ALPHA 0.2f
#define BETA 0.9f

// ---------------- probe mask element width ----------------
// Reads first 4096 32-bit words of the mask buffer (16 KB, safe under any dtype).
// If every word is 0, 1, or 1.0f-bits -> elements are 4-byte (int32/float32): flag=1.
// Otherwise (packed bool bytes land at arbitrary byte positions): flag=0.
__global__ void probe_mask(const uint32_t* __restrict__ m, int* __restrict__ flag) {
    int lane = threadIdx.x;  // 64 threads = 1 wave
    bool ok = true;
    for (int i = 0; i < 64; ++i) {
        uint32_t w = m[(size_t)i * 64 + lane];
        if (!(w == 0u || w == 1u || w == 0x3F800000u)) ok = false;
    }
    unsigned long long b = __ballot(ok);
    if (lane == 0) *flag = (b == ~0ull) ? 1 : 0;
}

// ---------------- build packed bitmask: [K][N][64] u64 ----------------
__global__ __launch_bounds__(256) void build_bits(const uint32_t* __restrict__ mraw,
                                                  const int* __restrict__ flag,
                                                  uint64_t* __restrict__ bits) {
    const int totalWords = KHOP * NN * (NN / 64);  // 524288
    int gt = blockIdx.x * blockDim.x + threadIdx.x;
    int gw = gt >> 6;
    int lane = threadIdx.x & 63;
    int nw = (gridDim.x * blockDim.x) >> 6;
    if (*flag) {  // 4-byte elements (int32 or float32) — nonzero word == true
        for (int w = gw; w < totalWords; w += nw) {
            uint32_t v = mraw[(size_t)w * 64 + lane];
            unsigned long long b = __ballot(v != 0u);
            if (lane == 0) bits[w] = b;
        }
    } else {      // 1-byte bool elements
        const uint8_t* m8 = (const uint8_t*)mraw;
        for (int w = gw; w < totalWords; w += nw) {
            uint8_t v = m8[(size_t)w * 64 + lane];
            unsigned long long b = __ballot(v != 0);
            if (lane == 0) bits[w] = b;
        }
    }
}

// ---------------- layer-1 GEMM: Wh[h,n,d] = sum_f x[n,f] W[h,f,d]; fused f1/f2 ----------------
// block 256: d4=(tid&15)*4 (4 d-values), q=tid>>4 (16 nodes/block). grid (N/16, H).
__global__ __launch_bounds__(256) void wh_gemm(const float* __restrict__ x,
                                               const float* __restrict__ W,
                                               const float* __restrict__ a1,
                                               const float* __restrict__ a2,
                                               float* __restrict__ Wh,
                                               float* __restrict__ f1,
                                               float* __restrict__ f2) {
    const int h = blockIdx.y;
    const int n0 = blockIdx.x * 16;
    const int tid = threadIdx.x;
    const int d4 = (tid & 15) * 4;
    const int q = tid >> 4;
    const int n = n0 + q;
    __shared__ float xs[16 * 65];  // +1 pad: q-stride 65 breaks bank aliasing
    float acc0 = 0.f, acc1 = 0.f, acc2 = 0.f, acc3 = 0.f;
    const float* Wp = W + (size_t)h * FIN * DD;
    const float* xp = x + (size_t)n * FIN;
    for (int fc = 0; fc < FIN; fc += 64) {
        float4 xv = *(const float4*)&xp[fc + d4];
        xs[q * 65 + d4 + 0] = xv.x;
        xs[q * 65 + d4 + 1] = xv.y;
        xs[q * 65 + d4 + 2] = xv.z;
        xs[q * 65 + d4 + 3] = xv.w;
        __syncthreads();
#pragma unroll 8
        for (int k = 0; k < 64; ++k) {
            float4 wv = *(const float4*)&Wp[(size_t)(fc + k) * DD + d4];
            float xb = xs[q * 65 + k];
            acc0 += xb * wv.x;
            acc1 += xb * wv.y;
            acc2 += xb * wv.z;
            acc3 += xb * wv.w;
        }
        __syncthreads();
    }
    size_t base = ((size_t)h * NN + n) * DD + d4;
    *(float4*)&Wh[base] = make_float4(acc0, acc1, acc2, acc3);
    // fused f1/f2 epilogue: reduce over d within each 16-lane group
    float4 a1v = *(const float4*)&a1[h * DD + d4];
    float4 a2v = *(const float4*)&a2[h * DD + d4];
    float p1 = acc0 * a1v.x + acc1 * a1v.y + acc2 * a1v.z + acc3 * a1v.w;
    float p2 = acc0 * a2v.x + acc1 * a2v.y + acc2 * a2v.z + acc3 * a2v.w;
    for (int off = 1; off < 16; off <<= 1) {
        p1 += __shfl_xor(p1, off);
        p2 += __shfl_xor(p2, off);
    }
    if ((tid & 15) == 0) { f1[h * NN + n] = p1; f2[h * NN + n] = p2; }
}

// ---------------- layer-1 attention: one block (512 thr) per node, all 8 heads ----------------
__global__ __launch_bounds__(512) void attn1(const uint64_t* __restrict__ bits,
                                             const float* __restrict__ Wh,
                                             const float* __restrict__ f1,
                                             const float* __restrict__ f2,
                                             float* __restrict__ x2) {
    const int n = blockIdx.x;
    const int tid = threadIdx.x;
    const int h = tid >> 6, d = tid & 63;
    __shared__ uint16_t nbr[NN];     // neighbor list (worst case full row)
    __shared__ float wts[HH * 512];  // per-head weights, batch of 512
    __shared__ float f1s[HH];
    __shared__ int cnt;
    if (tid < HH) f1s[tid] = f1[tid * NN + n];
    float res = 0.f;
    for (int hop = 0; hop < KHOP; ++hop) {
        __syncthreads();
        if (tid == 0) cnt = 0;
        __syncthreads();
        if (tid < 64) {  // wave 0 extracts set bits of this row's 64 bitmask words
            uint64_t v = bits[((size_t)hop * NN + n) * 64 + tid];
            int c = __popcll(v);
            int base = 0;
            if (c) base = atomicAdd(&cnt, c);
            int mb = tid * 64;
            while (v) {
                int j = __ffsll((unsigned long long)v) - 1;
                nbr[base++] = (uint16_t)(mb + j);
                v &= v - 1;
            }
        }
        __syncthreads();
        const int count = cnt;
        float acc = 0.f, den = 0.f;
        for (int b0 = 0; b0 < count; b0 += 512) {
            const int bs = min(512, count - b0);
            // weight phase: (head, j) pairs across all 512 threads
            for (int idx = tid; idx < HH * 512; idx += 512) {
                int hh = idx >> 9, j = idx & 511;
                if (j < bs) {
                    int m = nbr[b0 + j];
                    float e = f1s[hh] + f2[hh * NN + m];
                    e = (e > 0.f) ? e : ALPHA * e;
                    wts[idx] = __expf(e);
                }
            }
            __syncthreads();
            // accumulate phase: thread (h,d); Wh row load coalesced 256B/wave
            for (int j = 0; j < bs; ++j) {
                float w = wts[(h << 9) + j];
                int m = nbr[b0 + j];
                acc += w * Wh[((size_t)h * NN + m) * DD + d];
                den += w;
            }
            __syncthreads();
        }
        res += ((hop == 0) ? 1.f : BETA) * (acc / den);
    }
    float v = (res > 0.f) ? res : (__expf(res) - 1.f);  // elu
    x2[(size_t)n * (HH * DD) + tid] = v;                // tid == h*64+d: head concat
}

// ---------------- layer-2 GEMM: Who = x2 @ W_out; fused g1/g2 ----------------
__global__ __launch_bounds__(256) void who_gemm(const float* __restrict__ x2,
                                                const float* __restrict__ Wout,
                                                const float* __restrict__ ao1,
                                                const float* __restrict__ ao2,
                                                float* __restrict__ Who,
                                                float* __restrict__ g1,
                                                float* __restrict__ g2) {
    const int n0 = blockIdx.x * 16;
    const int tid = threadIdx.x;
    const int c = tid & 15, q = tid >> 4;
    const int n = n0 + q;
    __shared__ float wsh[FIN * CC];  // whole W_out: 32 KB
    __shared__ float xsh[16 * 65];
    for (int i = tid * 4; i < FIN * CC; i += 1024)
        *(float4*)&wsh[i] = *(const float4*)&Wout[i];
    float acc = 0.f;
    const int k4 = c * 4;
    for (int fc = 0; fc < FIN; fc += 64) {
        float4 xv = *(const float4*)&x2[(size_t)n * FIN + fc + k4];
        xsh[q * 65 + k4 + 0] = xv.x;
        xsh[q * 65 + k4 + 1] = xv.y;
        xsh[q * 65 + k4 + 2] = xv.z;
        xsh[q * 65 + k4 + 3] = xv.w;
        __syncthreads();
#pragma unroll
        for (int k = 0; k < 64; ++k)
            acc += xsh[q * 65 + k] * wsh[(fc + k) * CC + c];
        __syncthreads();
    }
    Who[n * CC + c] = acc;
    float p1 = acc * ao1[c];
    float p2 = acc * ao2[c];
    for (int off = 1; off < 16; off <<= 1) {
        p1 += __shfl_xor(p1, off);
        p2 += __shfl_xor(p2, off);
    }
    if (c == 0) { g1[n] = p1; g2[n] = p2; }
}

// ---------------- layer-2 attention + elu + log_softmax: one wave per node ----------------
__global__ __launch_bounds__(256) void attn2(const uint64_t* __restrict__ bits,
                                             const float* __restrict__ Who,
                                             const float* __restrict__ g1,
                                             const float* __restrict__ g2,
                                             float* __restrict__ out) {
    const int wv = threadIdx.x >> 6;
    const int lane = threadIdx.x & 63;
    const int n = blockIdx.x * 4 + wv;
    __shared__ uint16_t nbr[4][NN];  // per-wave neighbor list
    uint16_t* mynbr = nbr[wv];
    const float g1n = g1[n];
    const int c = lane & 15, s = lane >> 4;  // 16 classes x 4-way m-parallel
    float res = 0.f;
    for (int hop = 0; hop < KHOP; ++hop) {
        uint64_t v = bits[((size_t)hop * NN + n) * 64 + lane];
        int cpc = __popcll(v);
        int pref = cpc;  // inclusive prefix sum across wave
        for (int off = 1; off < 64; off <<= 1) {
            int t = __shfl_up(pref, off);
            if (lane >= off) pref += t;
        }
        int total = __shfl(pref, 63);
        int base = pref - cpc;
        int mb = lane * 64;
        while (v) {
            int j = __ffsll((unsigned long long)v) - 1;
            mynbr[base++] = (uint16_t)(mb + j);
            v &= v - 1;
        }
        __syncthreads();
        float acc = 0.f, den = 0.f;
        for (int j = s; j < total; j += 4) {
            int m = mynbr[j];
            float e = g1n + g2[m];
            e = (e > 0.f) ? e : ALPHA * e;
            float w = __expf(e);
            den += w;
            acc += w * Who[m * CC + c];
        }
        acc += __shfl_xor(acc, 16);
        acc += __shfl_xor(acc, 32);
        den += __shfl_xor(den, 16);
        den += __shfl_xor(den, 32);
        res += ((hop == 0) ? 1.f : BETA) * (acc / den);
        __syncthreads();
    }
    float o = (res > 0.f) ? res : (__expf(res) - 1.f);  // elu
    // log_softmax over 16 classes (replicated across the 4 s-groups)
    float mx = o;
    for (int off = 1; off < 16; off <<= 1) mx = fmaxf(mx, __shfl_xor(mx, off));
    float ex = __expf(o - mx);
    float sum = ex;
    for (int off = 1; off < 16; off <<= 1) sum += __shfl_xor(sum, off);
    float r = o - mx - __logf(sum);
    if (lane < 16) out[n * CC + c] = r;
}

extern "C" void kernel_launch(void* const* d_in, const int* in_sizes, int n_in,
                              void* d_out, int out_size, void* d_ws, size_t ws_size,
                              hipStream_t stream) {
    const float* x    = (const float*)d_in[0];
    const void*  masks= d_in[1];
    const float* W    = (const float*)d_in[2];
    const float* a1   = (const float*)d_in[3];
    const float* a2   = (const float*)d_in[4];
    const float* Wout = (const float*)d_in[5];
    const float* ao1  = (const float*)d_in[6];
    const float* ao2  = (const float*)d_in[7];
    float* out = (float*)d_out;

    char* ws = (char*)d_ws;
    int*      flag = (int*)ws;                              // 256 B slot
    uint64_t* bits = (uint64_t*)(ws + 256);                 // 4 MB
    float* Wh  = (float*)(ws + 256 + (size_t)KHOP * NN * 64 * 8);  // 8 MB
    float* f1  = Wh + (size_t)HH * NN * DD;                 // 128 KB
    float* f2  = f1 + (size_t)HH * NN;                      // 128 KB
    float* x2  = f2 + (size_t)HH * NN;                      // 8 MB
    float* Who = x2 + (size_t)NN * FIN;                     // 256 KB
    float* g1  = Who + (size_t)NN * CC;                     // 16 KB
    float* g2  = g1 + NN;                                   // 16 KB

    probe_mask<<<1, 64, 0, stream>>>((const uint32_t*)masks, flag);
    build_bits<<<2048, 256, 0, stream>>>((const uint32_t*)masks, flag, bits);
    wh_gemm<<<dim3(NN / 16, HH), 256, 0, stream>>>(x, W, a1, a2, Wh, f1, f2);
    attn1<<<NN, 512, 0, stream>>>(bits, Wh, f1, f2, x2);
    who_gemm<<<NN / 16, 256, 0, stream>>>(x2, Wout, ao1, ao2, Who, g1, g2);
    attn2<<<NN / 4, 256, 0, stream>>>(bits, Who, g1, g2, out);
    (void)in_sizes; (void)n_in; (void)out_size; (void)ws_size;
}

// Round 2
// 403.505 us; speedup vs baseline: 1.1750x; 1.1750x over previous
//
#include <hip/hip_runtime.h>
#include <cstdint>

#define NN 4096
#define FIN 512
#define DD 64
#define HH 8
#define CC 16
#define KHOP 2
#define ALPHA 0.2f
#define BETA 0.9f

// ---------------- probe mask element width ----------------
__global__ void probe_mask(const uint32_t* __restrict__ m, int* __restrict__ flag) {
    int lane = threadIdx.x;  // 64 threads = 1 wave
    bool ok = true;
    for (int i = 0; i < 64; ++i) {
        uint32_t w = m[(size_t)i * 64 + lane];
        if (!(w == 0u || w == 1u || w == 0x3F800000u)) ok = false;
    }
    unsigned long long b = __ballot(ok);
    if (lane == 0) *flag = (b == ~0ull) ? 1 : 0;
}

// ---------------- build packed bitmask: [K][N][64] u64 ----------------
__global__ __launch_bounds__(256) void build_bits(const uint32_t* __restrict__ mraw,
                                                  const int* __restrict__ flag,
                                                  uint64_t* __restrict__ bits) {
    const int totalWords = KHOP * NN * (NN / 64);  // 524288
    int gt = blockIdx.x * blockDim.x + threadIdx.x;
    int gw = gt >> 6;
    int lane = threadIdx.x & 63;
    int nw = (gridDim.x * blockDim.x) >> 6;
    if (*flag) {  // 4-byte elements (int32 or float32) — nonzero word == true
        for (int w = gw; w < totalWords; w += nw) {
            uint32_t v = mraw[(size_t)w * 64 + lane];
            unsigned long long b = __ballot(v != 0u);
            if (lane == 0) bits[w] = b;
        }
    } else {      // 1-byte bool elements
        const uint8_t* m8 = (const uint8_t*)mraw;
        for (int w = gw; w < totalWords; w += nw) {
            uint8_t v = m8[(size_t)w * 64 + lane];
            unsigned long long b = __ballot(v != 0);
            if (lane == 0) bits[w] = b;
        }
    }
}

// ---------------- layer-1 GEMM: Wh[h,n,d] = x @ W[h]; fused f1/f2 ----------------
// 64n x 64d tile per block; thread tile 4n x 4d (16 acc). grid (N/64, H), block 256.
// x tile staged k-major in LDS with XOR swizzle: element (k,n) lives at
//   k*64 + (((n>>2) ^ ((k + (k>>2)) & 15)) << 2) + (n&3)
// -> staging writes conflict-free, inner b128 reads aligned + conflict-free.
__global__ __launch_bounds__(256) void wh_gemm(const float* __restrict__ x,
                                               const float* __restrict__ W,
                                               const float* __restrict__ a1,
                                               const float* __restrict__ a2,
                                               float* __restrict__ Wh,
                                               float* __restrict__ f1,
                                               float* __restrict__ f2) {
    const int h = blockIdx.y;
    const int n0 = blockIdx.x * 64;
    const int tid = threadIdx.x;
    const int d4 = (tid & 15) * 4;   // d offset (varies across 16-lane group -> coalesced W/Wh)
    const int g = tid >> 4;          // node-group 0..15
    const int nq = g * 4;            // node offset in tile
    __shared__ float xs[64 * 64];    // 16 KB, swizzled
    float acc[4][4] = {};
    const float* Wp = W + (size_t)h * FIN * DD;

    for (int fc = 0; fc < FIN; fc += 64) {
        // stage x tile 64n x 64k transposed+swizzled
        {
            const int nl = tid >> 4;          // 0..15
            const int fl = (tid & 15) * 4;    // 0..60
#pragma unroll
            for (int r = 0; r < 4; ++r) {
                const int n = nl + r * 16;
                float4 xv = *(const float4*)&x[(size_t)(n0 + n) * FIN + fc + fl];
                const int ng = n >> 2, nb = n & 3;
                const float xe[4] = {xv.x, xv.y, xv.z, xv.w};
#pragma unroll
                for (int j = 0; j < 4; ++j) {
                    const int k = fl + j;
                    const int cg = ng ^ ((k + (k >> 2)) & 15);
                    xs[k * 64 + cg * 4 + nb] = xe[j];
                }
            }
        }
        __syncthreads();
#pragma unroll 4
        for (int k = 0; k < 64; ++k) {
            const int cg = g ^ ((k + (k >> 2)) & 15);
            float4 xv = *(const float4*)&xs[k * 64 + cg * 4];
            float4 wv = *(const float4*)&Wp[(size_t)(fc + k) * DD + d4];
            acc[0][0] += xv.x * wv.x; acc[0][1] += xv.x * wv.y; acc[0][2] += xv.x * wv.z; acc[0][3] += xv.x * wv.w;
            acc[1][0] += xv.y * wv.x; acc[1][1] += xv.y * wv.y; acc[1][2] += xv.y * wv.z; acc[1][3] += xv.y * wv.w;
            acc[2][0] += xv.z * wv.x; acc[2][1] += xv.z * wv.y; acc[2][2] += xv.z * wv.z; acc[2][3] += xv.z * wv.w;
            acc[3][0] += xv.w * wv.x; acc[3][1] += xv.w * wv.y; acc[3][2] += xv.w * wv.z; acc[3][3] += xv.w * wv.w;
        }
        __syncthreads();
    }

    const int nb0 = n0 + nq;
#pragma unroll
    for (int i = 0; i < 4; ++i) {
        size_t off = ((size_t)h * NN + nb0 + i) * DD + d4;
        *(float4*)&Wh[off] = make_float4(acc[i][0], acc[i][1], acc[i][2], acc[i][3]);
    }
    // fused f1/f2: reduce over d within each 16-lane group
    float4 a1v = *(const float4*)&a1[h * DD + d4];
    float4 a2v = *(const float4*)&a2[h * DD + d4];
    float p1[4], p2[4];
#pragma unroll
    for (int i = 0; i < 4; ++i) {
        p1[i] = acc[i][0] * a1v.x + acc[i][1] * a1v.y + acc[i][2] * a1v.z + acc[i][3] * a1v.w;
        p2[i] = acc[i][0] * a2v.x + acc[i][1] * a2v.y + acc[i][2] * a2v.z + acc[i][3] * a2v.w;
#pragma unroll
        for (int off = 1; off < 16; off <<= 1) {
            p1[i] += __shfl_xor(p1[i], off);
            p2[i] += __shfl_xor(p2[i], off);
        }
    }
    if ((tid & 15) == 0) {
#pragma unroll
        for (int i = 0; i < 4; ++i) {
            f1[h * NN + nb0 + i] = p1[i];
            f2[h * NN + nb0 + i] = p2[i];
        }
    }
}

// ---------------- layer-1 attention: block per node, wave per head ----------------
__global__ __launch_bounds__(512) void attn1(const uint64_t* __restrict__ bits,
                                             const float* __restrict__ Wh,
                                             const float* __restrict__ f1,
                                             const float* __restrict__ f2,
                                             float* __restrict__ x2) {
    const int n = blockIdx.x;
    const int tid = threadIdx.x;
    const int h = tid >> 6, lane = tid & 63;
    __shared__ uint16_t nbr[NN];
    __shared__ int cnt;
    const float f1n = f1[h * NN + n];
    const float* __restrict__ f2h = f2 + h * NN;
    const float* __restrict__ Whh = Wh + (size_t)h * NN * DD;
    float res = 0.f;
    for (int hop = 0; hop < KHOP; ++hop) {
        __syncthreads();
        if (tid == 0) cnt = 0;
        __syncthreads();
        if (tid < 64) {  // wave 0 extracts set bits of this row's 64 bitmask words
            uint64_t v = bits[((size_t)hop * NN + n) * 64 + tid];
            int c = __popcll(v);
            int base = 0;
            if (c) base = atomicAdd(&cnt, c);
            int mb = tid * 64;
            while (v) {
                int j = __ffsll((unsigned long long)v) - 1;
                nbr[base++] = (uint16_t)(mb + j);
                v &= v - 1;
            }
        }
        __syncthreads();
        const int count = cnt;
        float acc = 0.f, den = 0.f;
        for (int j = 0; j < count; ++j) {
            const int m = nbr[j];
            float e = f1n + f2h[m];
            e = (e > 0.f) ? e : ALPHA * e;
            const float w = __expf(e);
            den += w;
            acc += w * Whh[(size_t)m * DD + lane];
        }
        res += ((hop == 0) ? 1.f : BETA) * (acc / den);
    }
    float v = (res > 0.f) ? res : (__expf(res) - 1.f);  // elu
    x2[(size_t)n * (HH * DD) + tid] = v;                // tid == h*64+d: head concat
}

// ---------------- layer-2 GEMM: Who = x2 @ W_out; fused g1/g2 ----------------
__global__ __launch_bounds__(256) void who_gemm(const float* __restrict__ x2,
                                                const float* __restrict__ Wout,
                                                const float* __restrict__ ao1,
                                                const float* __restrict__ ao2,
                                                float* __restrict__ Who,
                                                float* __restrict__ g1,
                                                float* __restrict__ g2) {
    const int n0 = blockIdx.x * 16;
    const int tid = threadIdx.x;
    const int c = tid & 15, q = tid >> 4;
    const int n = n0 + q;
    __shared__ float wsh[FIN * CC];  // whole W_out: 32 KB
    __shared__ float xsh[16 * 65];
    for (int i = tid * 4; i < FIN * CC; i += 1024)
        *(float4*)&wsh[i] = *(const float4*)&Wout[i];
    float acc = 0.f;
    const int k4 = c * 4;
    for (int fc = 0; fc < FIN; fc += 64) {
        float4 xv = *(const float4*)&x2[(size_t)n * FIN + fc + k4];
        xsh[q * 65 + k4 + 0] = xv.x;
        xsh[q * 65 + k4 + 1] = xv.y;
        xsh[q * 65 + k4 + 2] = xv.z;
        xsh[q * 65 + k4 + 3] = xv.w;
        __syncthreads();
#pragma unroll
        for (int k = 0; k < 64; ++k)
            acc += xsh[q * 65 + k] * wsh[(fc + k) * CC + c];
        __syncthreads();
    }
    Who[n * CC + c] = acc;
    float p1 = acc * ao1[c];
    float p2 = acc * ao2[c];
    for (int off = 1; off < 16; off <<= 1) {
        p1 += __shfl_xor(p1, off);
        p2 += __shfl_xor(p2, off);
    }
    if (c == 0) { g1[n] = p1; g2[n] = p2; }
}

// ---------------- layer-2 attention + elu + log_softmax: one wave per node ----------------
__global__ __launch_bounds__(256) void attn2(const uint64_t* __restrict__ bits,
                                             const float* __restrict__ Who,
                                             const float* __restrict__ g1,
                                             const float* __restrict__ g2,
                                             float* __restrict__ out) {
    const int wv = threadIdx.x >> 6;
    const int lane = threadIdx.x & 63;
    const int n = blockIdx.x * 4 + wv;
    __shared__ uint16_t nbr[4][NN];  // per-wave neighbor list
    uint16_t* mynbr = nbr[wv];
    const float g1n = g1[n];
    const int c = lane & 15, s = lane >> 4;  // 16 classes x 4-way m-parallel
    float res = 0.f;
    for (int hop = 0; hop < KHOP; ++hop) {
        uint64_t v = bits[((size_t)hop * NN + n) * 64 + lane];
        int cpc = __popcll(v);
        int pref = cpc;  // inclusive prefix sum across wave
        for (int off = 1; off < 64; off <<= 1) {
            int t = __shfl_up(pref, off);
            if (lane >= off) pref += t;
        }
        int total = __shfl(pref, 63);
        int base = pref - cpc;
        int mb = lane * 64;
        while (v) {
            int j = __ffsll((unsigned long long)v) - 1;
            mynbr[base++] = (uint16_t)(mb + j);
            v &= v - 1;
        }
        __syncthreads();
        float acc = 0.f, den = 0.f;
        for (int j = s; j < total; j += 4) {
            int m = mynbr[j];
            float e = g1n + g2[m];
            e = (e > 0.f) ? e : ALPHA * e;
            float w = __expf(e);
            den += w;
            acc += w * Who[m * CC + c];
        }
        acc += __shfl_xor(acc, 16);
        acc += __shfl_xor(acc, 32);
        den += __shfl_xor(den, 16);
        den += __shfl_xor(den, 32);
        res += ((hop == 0) ? 1.f : BETA) * (acc / den);
        __syncthreads();
    }
    float o = (res > 0.f) ? res : (__expf(res) - 1.f);  // elu
    float mx = o;
    for (int off = 1; off < 16; off <<= 1) mx = fmaxf(mx, __shfl_xor(mx, off));
    float ex = __expf(o - mx);
    float sum = ex;
    for (int off = 1; off < 16; off <<= 1) sum += __shfl_xor(sum, off);
    float r = o - mx - __logf(sum);
    if (lane < 16) out[n * CC + c] = r;
}

extern "C" void kernel_launch(void* const* d_in, const int* in_sizes, int n_in,
                              void* d_out, int out_size, void* d_ws, size_t ws_size,
                              hipStream_t stream) {
    const float* x    = (const float*)d_in[0];
    const void*  masks= d_in[1];
    const float* W    = (const float*)d_in[2];
    const float* a1   = (const float*)d_in[3];
    const float* a2   = (const float*)d_in[4];
    const float* Wout = (const float*)d_in[5];
    const float* ao1  = (const float*)d_in[6];
    const float* ao2  = (const float*)d_in[7];
    float* out = (float*)d_out;

    char* ws = (char*)d_ws;
    int*      flag = (int*)ws;                              // 256 B slot
    uint64_t* bits = (uint64_t*)(ws + 256);                 // 4 MB
    float* Wh  = (float*)(ws + 256 + (size_t)KHOP * NN * 64 * 8);  // 8 MB
    float* f1  = Wh + (size_t)HH * NN * DD;                 // 128 KB
    float* f2  = f1 + (size_t)HH * NN;                      // 128 KB
    float* x2  = f2 + (size_t)HH * NN;                      // 8 MB
    float* Who = x2 + (size_t)NN * FIN;                     // 256 KB
    float* g1  = Who + (size_t)NN * CC;                     // 16 KB
    float* g2  = g1 + NN;                                   // 16 KB

    probe_mask<<<1, 64, 0, stream>>>((const uint32_t*)masks, flag);
    build_bits<<<2048, 256, 0, stream>>>((const uint32_t*)masks, flag, bits);
    wh_gemm<<<dim3(NN / 64, HH), 256, 0, stream>>>(x, W, a1, a2, Wh, f1, f2);
    attn1<<<NN, 512, 0, stream>>>(bits, Wh, f1, f2, x2);
    who_gemm<<<NN / 16, 256, 0, stream>>>(x2, Wout, ao1, ao2, Who, g1, g2);
    attn2<<<NN / 4, 256, 0, stream>>>(bits, Who, g1, g2, out);
    (void)in_sizes; (void)n_in; (void)out_size; (void)ws_size;
}

// Round 3
// 393.388 us; speedup vs baseline: 1.2052x; 1.0257x over previous
//
#include <hip/hip_runtime.h>
#include <cstdint>

#define NN 4096
#define FIN 512
#define DD 64
#define HH 8
#define CC 16
#define KHOP 2
#define ALPHA 0.2f
#define BETA 0.9f

static __device__ __forceinline__ uint16_t f2bf(float f) {  // RTNE
    uint32_t u = __float_as_uint(f);
    u += 0x7FFFu + ((u >> 16) & 1u);
    return (uint16_t)(u >> 16);
}
static __device__ __forceinline__ float bf2f(uint16_t b) {
    return __uint_as_float(((uint32_t)b) << 16);
}

// ---------------- probe mask element width ----------------
__global__ void probe_mask(const uint32_t* __restrict__ m, int* __restrict__ flag) {
    int lane = threadIdx.x;  // 64 threads = 1 wave
    bool ok = true;
    for (int i = 0; i < 64; ++i) {
        uint32_t w = m[(size_t)i * 64 + lane];
        if (!(w == 0u || w == 1u || w == 0x3F800000u)) ok = false;
    }
    unsigned long long b = __ballot(ok);
    if (lane == 0) *flag = (b == ~0ull) ? 1 : 0;
}

// ---------------- build packed bitmask: [K][N][64] u64 ----------------
__global__ __launch_bounds__(256) void build_bits(const uint32_t* __restrict__ mraw,
                                                  const int* __restrict__ flag,
                                                  uint64_t* __restrict__ bits) {
    const int totalWords = KHOP * NN * (NN / 64);  // 524288
    int gt = blockIdx.x * blockDim.x + threadIdx.x;
    int gw = gt >> 6;
    int lane = threadIdx.x & 63;
    int nw = (gridDim.x * blockDim.x) >> 6;
    if (*flag) {  // 4-byte elements (int32 or float32) — nonzero word == true
        for (int w = gw; w < totalWords; w += nw) {
            uint32_t v = mraw[(size_t)w * 64 + lane];
            unsigned long long b = __ballot(v != 0u);
            if (lane == 0) bits[w] = b;
        }
    } else {      // 1-byte bool elements
        const uint8_t* m8 = (const uint8_t*)mraw;
        for (int w = gw; w < totalWords; w += nw) {
            uint8_t v = m8[(size_t)w * 64 + lane];
            unsigned long long b = __ballot(v != 0);
            if (lane == 0) bits[w] = b;
        }
    }
}

// ---------------- layer-1 GEMM: Wh[h,n,d] = x @ W[h]; bf16 out; fused f1/f2 ----------------
// 64n x 64d tile per block; thread tile 4n x 4d. grid (N/64, H), block 256.
// x tile k-major in LDS, XOR-swizzled: (k,n) -> k*64 + ((n>>2)^((k+(k>>2))&15))*4 + (n&3)
__global__ __launch_bounds__(256) void wh_gemm(const float* __restrict__ x,
                                               const float* __restrict__ W,
                                               const float* __restrict__ a1,
                                               const float* __restrict__ a2,
                                               uint16_t* __restrict__ Whb,
                                               float* __restrict__ f1,
                                               float* __restrict__ f2) {
    const int h = blockIdx.y;
    const int n0 = blockIdx.x * 64;
    const int tid = threadIdx.x;
    const int d4 = (tid & 15) * 4;
    const int g = tid >> 4;
    const int nq = g * 4;
    __shared__ float xs[64 * 64];
    float acc[4][4] = {};
    const float* Wp = W + (size_t)h * FIN * DD;

    for (int fc = 0; fc < FIN; fc += 64) {
        {
            const int nl = tid >> 4;
            const int fl = (tid & 15) * 4;
#pragma unroll
            for (int r = 0; r < 4; ++r) {
                const int n = nl + r * 16;
                float4 xv = *(const float4*)&x[(size_t)(n0 + n) * FIN + fc + fl];
                const int ng = n >> 2, nb = n & 3;
                const float xe[4] = {xv.x, xv.y, xv.z, xv.w};
#pragma unroll
                for (int j = 0; j < 4; ++j) {
                    const int k = fl + j;
                    const int cg = ng ^ ((k + (k >> 2)) & 15);
                    xs[k * 64 + cg * 4 + nb] = xe[j];
                }
            }
        }
        __syncthreads();
#pragma unroll 4
        for (int k = 0; k < 64; ++k) {
            const int cg = g ^ ((k + (k >> 2)) & 15);
            float4 xv = *(const float4*)&xs[k * 64 + cg * 4];
            float4 wv = *(const float4*)&Wp[(size_t)(fc + k) * DD + d4];
            acc[0][0] += xv.x * wv.x; acc[0][1] += xv.x * wv.y; acc[0][2] += xv.x * wv.z; acc[0][3] += xv.x * wv.w;
            acc[1][0] += xv.y * wv.x; acc[1][1] += xv.y * wv.y; acc[1][2] += xv.y * wv.z; acc[1][3] += xv.y * wv.w;
            acc[2][0] += xv.z * wv.x; acc[2][1] += xv.z * wv.y; acc[2][2] += xv.z * wv.z; acc[2][3] += xv.z * wv.w;
            acc[3][0] += xv.w * wv.x; acc[3][1] += xv.w * wv.y; acc[3][2] += xv.w * wv.z; acc[3][3] += xv.w * wv.w;
        }
        __syncthreads();
    }

    const int nb0 = n0 + nq;
#pragma unroll
    for (int i = 0; i < 4; ++i) {
        ushort4 o;
        o.x = f2bf(acc[i][0]); o.y = f2bf(acc[i][1]);
        o.z = f2bf(acc[i][2]); o.w = f2bf(acc[i][3]);
        *(ushort4*)&Whb[((size_t)h * NN + nb0 + i) * DD + d4] = o;
    }
    float4 a1v = *(const float4*)&a1[h * DD + d4];
    float4 a2v = *(const float4*)&a2[h * DD + d4];
    float p1[4], p2[4];
#pragma unroll
    for (int i = 0; i < 4; ++i) {
        p1[i] = acc[i][0] * a1v.x + acc[i][1] * a1v.y + acc[i][2] * a1v.z + acc[i][3] * a1v.w;
        p2[i] = acc[i][0] * a2v.x + acc[i][1] * a2v.y + acc[i][2] * a2v.z + acc[i][3] * a2v.w;
#pragma unroll
        for (int off = 1; off < 16; off <<= 1) {
            p1[i] += __shfl_xor(p1[i], off);
            p2[i] += __shfl_xor(p2[i], off);
        }
    }
    if ((tid & 15) == 0) {
#pragma unroll
        for (int i = 0; i < 4; ++i) {
            f1[h * NN + nb0 + i] = p1[i];
            f2[h * NN + nb0 + i] = p2[i];
        }
    }
}

// ---------------- layer-1 attention: block per node, wave per head ----------------
// Weights computed lane-parallel (one exp per head-edge), broadcast via readlane.
__global__ __launch_bounds__(512) void attn1(const uint64_t* __restrict__ bits,
                                             const uint16_t* __restrict__ Whb,
                                             const float* __restrict__ f1,
                                             const float* __restrict__ f2,
                                             float* __restrict__ x2) {
    const int n = blockIdx.x;
    const int tid = threadIdx.x;
    const int h = tid >> 6, lane = tid & 63;
    __shared__ uint16_t nbr[NN];
    __shared__ int cnt;
    const float f1n = f1[h * NN + n];
    const float* __restrict__ f2h = f2 + h * NN;
    const uint16_t* __restrict__ Whl = Whb + (size_t)h * NN * DD + lane;
    float res = 0.f;
    for (int hop = 0; hop < KHOP; ++hop) {
        __syncthreads();
        if (tid == 0) cnt = 0;
        __syncthreads();
        if (tid < 64) {  // wave 0 extracts set bits of this row's 64 bitmask words
            uint64_t v = bits[((size_t)hop * NN + n) * 64 + tid];
            int c = __popcll(v);
            int base = 0;
            if (c) base = atomicAdd(&cnt, c);
            int mb = tid * 64;
            while (v) {
                int j = __ffsll((unsigned long long)v) - 1;
                nbr[base++] = (uint16_t)(mb + j);
                v &= v - 1;
            }
        }
        __syncthreads();
        const int count = cnt;
        float acc = 0.f, denp = 0.f;
        for (int b0 = 0; b0 < count; b0 += 64) {
            const int bs = min(64, count - b0);
            int m = 0; float w = 0.f;
            if (lane < bs) {
                m = nbr[b0 + lane];
                float e = f1n + f2h[m];
                e = (e > 0.f) ? e : ALPHA * e;
                w = __expf(e);
            }
            denp += w;
            const int bsp = (bs + 7) & ~7;  // pad lanes have w=0,m=0 (harmless row-0 load)
            for (int j0 = 0; j0 < bsp; j0 += 8) {
#pragma unroll
                for (int jj = 0; jj < 8; ++jj) {
                    const int j = j0 + jj;
                    const float wj = __uint_as_float(__builtin_amdgcn_readlane(__float_as_uint(w), j));
                    const int mj = __builtin_amdgcn_readlane(m, j);
                    acc += wj * bf2f(Whl[(size_t)mj * DD]);
                }
            }
        }
        float den = denp;
#pragma unroll
        for (int off = 1; off < 64; off <<= 1) den += __shfl_xor(den, off);
        res += ((hop == 0) ? 1.f : BETA) * (acc / den);
    }
    float v = (res > 0.f) ? res : (__expf(res) - 1.f);  // elu
    x2[(size_t)n * (HH * DD) + tid] = v;                // tid == h*64+d: head concat
}

// ---------------- layer-2 GEMM: Who = x2 @ W_out; fused g1/g2 ----------------
__global__ __launch_bounds__(256) void who_gemm(const float* __restrict__ x2,
                                                const float* __restrict__ Wout,
                                                const float* __restrict__ ao1,
                                                const float* __restrict__ ao2,
                                                float* __restrict__ Who,
                                                float* __restrict__ g1,
                                                float* __restrict__ g2) {
    const int n0 = blockIdx.x * 16;
    const int tid = threadIdx.x;
    const int c = tid & 15, q = tid >> 4;
    const int n = n0 + q;
    __shared__ float wsh[FIN * CC];  // whole W_out: 32 KB
    __shared__ float xsh[16 * 65];
    for (int i = tid * 4; i < FIN * CC; i += 1024)
        *(float4*)&wsh[i] = *(const float4*)&Wout[i];
    float acc = 0.f;
    const int k4 = c * 4;
    for (int fc = 0; fc < FIN; fc += 64) {
        float4 xv = *(const float4*)&x2[(size_t)n * FIN + fc + k4];
        xsh[q * 65 + k4 + 0] = xv.x;
        xsh[q * 65 + k4 + 1] = xv.y;
        xsh[q * 65 + k4 + 2] = xv.z;
        xsh[q * 65 + k4 + 3] = xv.w;
        __syncthreads();
#pragma unroll
        for (int k = 0; k < 64; ++k)
            acc += xsh[q * 65 + k] * wsh[(fc + k) * CC + c];
        __syncthreads();
    }
    Who[n * CC + c] = acc;
    float p1 = acc * ao1[c];
    float p2 = acc * ao2[c];
    for (int off = 1; off < 16; off <<= 1) {
        p1 += __shfl_xor(p1, off);
        p2 += __shfl_xor(p2, off);
    }
    if (c == 0) { g1[n] = p1; g2[n] = p2; }
}

// ---------------- layer-2 attention + elu + log_softmax: one wave per node ----------------
__global__ __launch_bounds__(256) void attn2(const uint64_t* __restrict__ bits,
                                             const float* __restrict__ Who,
                                             const float* __restrict__ g1,
                                             const float* __restrict__ g2,
                                             float* __restrict__ out) {
    const int wv = threadIdx.x >> 6;
    const int lane = threadIdx.x & 63;
    const int n = blockIdx.x * 4 + wv;
    __shared__ uint16_t nbr[4][NN];  // per-wave neighbor list
    uint16_t* mynbr = nbr[wv];
    const float g1n = g1[n];
    const int c = lane & 15, s = lane >> 4;  // 16 classes x 4-way m-parallel
    float res = 0.f;
    for (int hop = 0; hop < KHOP; ++hop) {
        uint64_t v = bits[((size_t)hop * NN + n) * 64 + lane];
        int cpc = __popcll(v);
        int pref = cpc;  // inclusive prefix sum across wave
        for (int off = 1; off < 64; off <<= 1) {
            int t = __shfl_up(pref, off);
            if (lane >= off) pref += t;
        }
        int total = __shfl(pref, 63);
        int base = pref - cpc;
        int mb = lane * 64;
        while (v) {
            int j = __ffsll((unsigned long long)v) - 1;
            mynbr[base++] = (uint16_t)(mb + j);
            v &= v - 1;
        }
        __syncthreads();
        float acc = 0.f, den = 0.f;
        for (int j = s; j < total; j += 4) {
            int m = mynbr[j];
            float e = g1n + g2[m];
            e = (e > 0.f) ? e : ALPHA * e;
            float w = __expf(e);
            den += w;
            acc += w * Who[m * CC + c];
        }
        acc += __shfl_xor(acc, 16);
        acc += __shfl_xor(acc, 32);
        den += __shfl_xor(den, 16);
        den += __shfl_xor(den, 32);
        res += ((hop == 0) ? 1.f : BETA) * (acc / den);
        __syncthreads();
    }
    float o = (res > 0.f) ? res : (__expf(res) - 1.f);  // elu
    float mx = o;
    for (int off = 1; off < 16; off <<= 1) mx = fmaxf(mx, __shfl_xor(mx, off));
    float ex = __expf(o - mx);
    float sum = ex;
    for (int off = 1; off < 16; off <<= 1) sum += __shfl_xor(sum, off);
    float r = o - mx - __logf(sum);
    if (lane < 16) out[n * CC + c] = r;
}

extern "C" void kernel_launch(void* const* d_in, const int* in_sizes, int n_in,
                              void* d_out, int out_size, void* d_ws, size_t ws_size,
                              hipStream_t stream) {
    const float* x    = (const float*)d_in[0];
    const void*  masks= d_in[1];
    const float* W    = (const float*)d_in[2];
    const float* a1   = (const float*)d_in[3];
    const float* a2   = (const float*)d_in[4];
    const float* Wout = (const float*)d_in[5];
    const float* ao1  = (const float*)d_in[6];
    const float* ao2  = (const float*)d_in[7];
    float* out = (float*)d_out;

    char* ws = (char*)d_ws;
    int*      flag = (int*)ws;                              // 256 B slot
    uint64_t* bits = (uint64_t*)(ws + 256);                 // 4 MB
    uint16_t* Whb  = (uint16_t*)(ws + 256 + (size_t)KHOP * NN * 64 * 8);  // 4 MB (bf16)
    float* f1  = (float*)(Whb + (size_t)HH * NN * DD);      // 128 KB
    float* f2  = f1 + (size_t)HH * NN;                      // 128 KB
    float* x2  = f2 + (size_t)HH * NN;                      // 8 MB
    float* Who = x2 + (size_t)NN * FIN;                     // 256 KB
    float* g1  = Who + (size_t)NN * CC;                     // 16 KB
    float* g2  = g1 + NN;                                   // 16 KB

    probe_mask<<<1, 64, 0, stream>>>((const uint32_t*)masks, flag);
    build_bits<<<2048, 256, 0, stream>>>((const uint32_t*)masks, flag, bits);
    wh_gemm<<<dim3(NN / 64, HH), 256, 0, stream>>>(x, W, a1, a2, Whb, f1, f2);
    attn1<<<NN, 512, 0, stream>>>(bits, Whb, f1, f2, x2);
    who_gemm<<<NN / 16, 256, 0, stream>>>(x2, Wout, ao1, ao2, Who, g1, g2);
    attn2<<<NN / 4, 256, 0, stream>>>(bits, Who, g1, g2, out);
    (void)in_sizes; (void)n_in; (void)out_size; (void)ws_size;
}